// Round 3
// 138.870 us; speedup vs baseline: 1.0020x; 1.0020x over previous
//
#include <hip/hip_runtime.h>
#include <stdint.h>

// OctonionLinear == GEMM: out[b, i*8+k] = sum_{j,p} x[b, j*8+p] * W[i,j,p,k] + bias[i,k]
// M=512, N=4096, K=4096, fp32 in/out, bf16 MFMA.
// R10 == R8/R9 resubmit (both died to container-acquisition infra, no signal).
//  Restore the m97-proven GEMM geometry for the K-split inner kernel.
//  R7 used 8 waves x (64x32) = 8 MFMA/wave/barrier, 0.75 ds_read/MFMA.
//  The ladder-verified shape (912 TF @ 4096^3) is 4 waves x (64x64), 4x4 acc,
//  BK=32: 16 MFMA/wave/barrier, 0.5 ds_read/MFMA, 32KB dbuf LDS,
//  4x global_load_lds(16B)/thread/iter. Same 128x128 tile, same KSPLIT=4
//  partial-store + reduce epilogue (R2 showed atomics cost ~16us).
// prep: W-transpose + x-convert; bias-init only in atomic fallback.

#define M_DIM 512
#define N_DIM 4096
#define K_DIM 4096
#define KSPLIT 4
#define KC (K_DIM / KSPLIT)                    // 1024
#define NIT (KC / 32)                          // 32
#define PART_ELEMS (M_DIM * N_DIM)             // 2097152 floats per z-slice

typedef __bf16 bf16x8 __attribute__((ext_vector_type(8)));
typedef float f32x4 __attribute__((ext_vector_type(4)));

__device__ inline unsigned short f2bf(float f) {
  union { float f; unsigned int u; } v;
  v.f = f;
  unsigned int u = v.u;
  unsigned int r = (u + 0x7fffu + ((u >> 16) & 1u)) >> 16;  // RNE
  return (unsigned short)r;
}

// blocks [0,4096): W transpose+convert -> bt[nn][kk], coalesced 16KB chunks.
// blocks [4096,5120): x convert -> abf, 8 el/thread.
// blocks [5120,7168): out = bias broadcast (ONLY launched in atomic path).
__global__ __launch_bounds__(256) void prep_kernel(
    const float* __restrict__ x, const float* __restrict__ w,
    const float* __restrict__ bias, unsigned short* __restrict__ abf,
    unsigned short* __restrict__ bt, float* __restrict__ out) {
  const int bid = blockIdx.x;
  const int t = threadIdx.x;
  if (bid < 4096) {
    __shared__ __align__(16) unsigned short lT[8][512];  // [k][j'*8+p], 8KB
    const int i = bid >> 3;
    const int jg = bid & 7;
    const float4* src =
        (const float4*)(w + (size_t)i * 32768 + jg * 4096 + t * 16);
    float4 v0 = src[0], v1 = src[1], v2 = src[2], v3 = src[3];
    const int jp = (t >> 2) * 8 + (t & 3) * 2;  // j'*8 + p0 (even)
    const float* lo = (const float*)&v0;  // k=0..3, p0   (v1: k=4..7)
    const float* hi = (const float*)&v2;  // k=0..3, p0+1 (v3: k=4..7)
#pragma unroll
    for (int k = 0; k < 4; ++k) {
      unsigned int pk =
          (unsigned int)f2bf(lo[k]) | ((unsigned int)f2bf(hi[k]) << 16);
      *(unsigned int*)&lT[k][jp] = pk;
    }
    lo = (const float*)&v1;
    hi = (const float*)&v3;
#pragma unroll
    for (int k = 0; k < 4; ++k) {
      unsigned int pk =
          (unsigned int)f2bf(lo[k]) | ((unsigned int)f2bf(hi[k]) << 16);
      *(unsigned int*)&lT[k + 4][jp] = pk;
    }
    __syncthreads();
    const int r = t >> 5, c = t & 31;  // 32B/thread, 1KB contiguous runs
    const uint4* s = (const uint4*)&lT[r][c * 16];
    uint4* d = (uint4*)(bt + (size_t)(i * 8 + r) * K_DIM + jg * 512 + c * 16);
    d[0] = s[0];
    d[1] = s[1];
  } else if (bid < 5120) {
    int g = (bid - 4096) * 256 + t;  // [0, 262144); 8 elements each
    const float4* xi = (const float4*)x;
    float4 a = xi[g * 2];
    float4 b = xi[g * 2 + 1];
    __attribute__((aligned(16))) unsigned short o[8] = {
        f2bf(a.x), f2bf(a.y), f2bf(a.z), f2bf(a.w),
        f2bf(b.x), f2bf(b.y), f2bf(b.z), f2bf(b.w)};
    *(uint4*)(abf + (size_t)g * 8) = *(const uint4*)o;
  } else {
    int g = (bid - 5120) * 256 + t;  // [0, 524288); 4 elements each
    int el = g * 4;
    int col = el & (N_DIM - 1);
    *(float4*)(out + el) = *(const float4*)(bias + col);
  }
}

__device__ inline void gld16(const void* g, void* l) {
  __builtin_amdgcn_global_load_lds(
      (const __attribute__((address_space(1))) unsigned int*)g,
      (__attribute__((address_space(3))) unsigned int*)l, 16, 0, 0);
}

// Tile 128M x 128N, BK=32, 256 threads = 4 waves, wave-tile 64M x 64N (4x4).
// LDS: A 128x32 (8KB) + B 128x32 (8KB) per buffer, dbuf = 32KB.
// m97-proven geometry: 16 MFMA + 8 ds_read_b128 per wave per barrier.
__global__ __launch_bounds__(256) void gemm_kernel(
    const unsigned short* __restrict__ A, const unsigned short* __restrict__ Bt,
    float* __restrict__ out, float* __restrict__ part, int use_atomic) {
  __shared__ __align__(16) char lds[2][16 * 1024];
  const int t = threadIdx.x;
  const int n0 = blockIdx.x * 128;
  const int m0 = blockIdx.y * 128;
  const int z = blockIdx.z;
  const int kc0 = z * KC;
  const int w = t >> 6;
  const int lane = t & 63;
  const int wr = w >> 1;     // 0..1 -> 64 M-rows
  const int wc = w & 1;      // 0..1 -> 64 N-cols
  const int lrow = lane & 15;
  const int kb = lane >> 4;  // k-block 0..3 (8 bf16 each)

  f32x4 acc[4][4] = {};

  // staging: each thread 2 A-segs + 2 B-segs of 16B.
  // LDS dest = wave-uniform base (w*1024 + seg*4096) + lane*16 == seg*4096+t*16.
  const int srow = t >> 2;        // 0..63
  const int scol = (t & 3) * 8;   // element col (16B-aligned)
  const size_t aOff0 = (size_t)(m0 + srow) * K_DIM + kc0 + scol;
  const size_t aOff1 = aOff0 + (size_t)64 * K_DIM;
  const size_t bOff0 = (size_t)(n0 + srow) * K_DIM + kc0 + scol;
  const size_t bOff1 = bOff0 + (size_t)64 * K_DIM;

  auto issue = [&](int it) {
    char* buf = lds[it & 1];
    gld16(A + aOff0 + it * 32, buf + t * 16);
    gld16(A + aOff1 + it * 32, buf + 4096 + t * 16);
    gld16(Bt + bOff0 + it * 32, buf + 8192 + t * 16);
    gld16(Bt + bOff1 + it * 32, buf + 12288 + t * 16);
  };

  issue(0);
  for (int it = 0; it < NIT; ++it) {
    __syncthreads();
    if (it + 1 < NIT) issue(it + 1);
    const unsigned short* cA = (const unsigned short*)lds[it & 1];
    const unsigned short* cB = cA + 4096;  // +8KB

    bf16x8 af[4], bfr[4];
#pragma unroll
    for (int mt = 0; mt < 4; ++mt)
      af[mt] = *(const bf16x8*)(cA + (wr * 64 + mt * 16 + lrow) * 32 + kb * 8);
#pragma unroll
    for (int nt = 0; nt < 4; ++nt)
      bfr[nt] = *(const bf16x8*)(cB + (wc * 64 + nt * 16 + lrow) * 32 + kb * 8);
#pragma unroll
    for (int mt = 0; mt < 4; ++mt)
#pragma unroll
      for (int nt = 0; nt < 4; ++nt)
        acc[mt][nt] = __builtin_amdgcn_mfma_f32_16x16x32_bf16(
            af[mt], bfr[nt], acc[mt][nt], 0, 0, 0);
  }

  // C/D layout (verified m89/m91): col = lane&15, row = (lane>>4)*4 + reg
#pragma unroll
  for (int mt = 0; mt < 4; ++mt) {
    const int gmb = m0 + wr * 64 + mt * 16 + kb * 4;
#pragma unroll
    for (int nt = 0; nt < 4; ++nt) {
      const int gn = n0 + wc * 64 + nt * 16 + lrow;
      if (use_atomic) {
#pragma unroll
        for (int r = 0; r < 4; ++r)
          atomicAdd(out + (size_t)(gmb + r) * N_DIM + gn, acc[mt][nt][r]);
      } else {
        float* p = part + (size_t)z * PART_ELEMS;
#pragma unroll
        for (int r = 0; r < 4; ++r)
          p[(size_t)(gmb + r) * N_DIM + gn] = acc[mt][nt][r];
      }
    }
  }
}

// out = sum_z part[z] + bias ; 2048 blocks x 256 thr x 1 float4
__global__ __launch_bounds__(256) void reduce_kernel(
    const float* __restrict__ part, const float* __restrict__ bias,
    float* __restrict__ out) {
  const int g = blockIdx.x * 256 + threadIdx.x;  // [0, 524288)
  const float4* p = (const float4*)part;
  const float4* b4 = (const float4*)bias;
  const int Q = PART_ELEMS / 4;  // 524288
  float4 s0 = p[g];
  float4 s1 = p[g + Q];
  float4 s2 = p[g + 2 * Q];
  float4 s3 = p[g + 3 * Q];
  float4 bb = b4[g & (N_DIM / 4 - 1)];
  float4 r;
  r.x = s0.x + s1.x + s2.x + s3.x + bb.x;
  r.y = s0.y + s1.y + s2.y + s3.y + bb.y;
  r.z = s0.z + s1.z + s2.z + s3.z + bb.z;
  r.w = s0.w + s1.w + s2.w + s3.w + bb.w;
  ((float4*)out)[g] = r;
}

extern "C" void kernel_launch(void* const* d_in, const int* in_sizes, int n_in,
                              void* d_out, int out_size, void* d_ws,
                              size_t ws_size, hipStream_t stream) {
  const float* x = (const float*)d_in[0];     // [512, 4096]
  const float* w = (const float*)d_in[1];     // [512, 512, 8, 8]
  const float* bias = (const float*)d_in[2];  // [512, 8]
  float* out = (float*)d_out;                 // [512, 4096]

  unsigned short* abf = (unsigned short*)d_ws;       // [0, 4MB) bf16 A
  unsigned short* bt = abf + (size_t)M_DIM * K_DIM;  // [4MB, 36MB) bf16 B^T
  float* part = (float*)((char*)d_ws + 36u * 1024 * 1024);  // [36MB, 68MB)

  const bool have_ws = ws_size >= 68ull * 1024 * 1024;
  const int use_atomic = have_ws ? 0 : 1;

  // bias-init segment only needed for the atomic path
  prep_kernel<<<use_atomic ? 7168 : 5120, 256, 0, stream>>>(x, w, bias, abf,
                                                            bt, out);

  dim3 grid(N_DIM / 128, M_DIM / 128, KSPLIT);  // 32 x 4 x 4 = 512 blocks
  gemm_kernel<<<grid, 256, 0, stream>>>(abf, bt, out, part, use_atomic);

  if (!use_atomic)
    reduce_kernel<<<PART_ELEMS / 4 / 256, 256, 0, stream>>>(part, bias, out);
}